// Round 2
// 660.806 us; speedup vs baseline: 1.1760x; 1.1760x over previous
//
#include <hip/hip_runtime.h>
#include <cmath>

#define NEG -1e9f
#define LOG2E 1.44269504088896340736f
constexpr int B = 8, N = 512, M = 512, D = 512;
constexpr size_t NM = (size_t)N * M;   // 262144

constexpr int NCHUNK = 138;     // multiple of 3; compute chunks end at 134

// Native-hardware transcendentals (v_exp_f32 = 2^x, v_log_f32 = log2 x).
#define EXP2F(x) __builtin_amdgcn_exp2f(x)
#define LOG2F(x) __builtin_amdgcn_logf(x)

// DPP full-wave shifts (register-file; replaces ds_bpermute).
__device__ __forceinline__ float dpp_shr1(float v) {
    return __int_as_float(__builtin_amdgcn_update_dpp(
        __float_as_int(v), __float_as_int(v), 0x138, 0xf, 0xf, false));
}
__device__ __forceinline__ float dpp_shl1(float v) {
    return __int_as_float(__builtin_amdgcn_update_dpp(
        __float_as_int(v), __float_as_int(v), 0x130, 0xf, 0xf, false));
}

// Compact diagonal layout: cell (r,c) 0-based -> diag_off(kd) + r - max(0,kd-511)
__device__ __forceinline__ int diag_off(int kd) {
    return (kd <= 511) ? ((kd * (kd + 1)) >> 1)
                       : ((int)NM - (((1023 - kd) * (1024 - kd)) >> 1));
}
__device__ __forceinline__ int diag_flat_clamped(int kd, int r) {
    const int k = min(max(kd, 0), 1022);
    const int f = diag_off(k) + r - max(0, k - 511);
    return min(max(f, 0), (int)NM - 1);
}

// ---------------------------------------------------------------------------
// GEMM + activation: which=0 -> theta = softplus(zx . zy^T)
//                    which=1 -> A     = log_sigmoid(gx . gy^T)
// ---------------------------------------------------------------------------
__global__ __launch_bounds__(256)
void gemm_act_kernel(const float* __restrict__ zx, const float* __restrict__ zy,
                     const float* __restrict__ gx, const float* __restrict__ gy,
                     float* __restrict__ out_theta, float* __restrict__ out_A)
{
    const int bz = blockIdx.z;
    const int b = bz >> 1, which = bz & 1;
    const float* X = (which ? gx : zx) + (size_t)b * N * D;
    const float* Y = (which ? gy : zy) + (size_t)b * M * D;
    float* C = (which ? out_A : out_theta) + (size_t)b * NM;

    __shared__ float Xs[16][68];
    __shared__ float Ys[16][68];

    const int tx = threadIdx.x, ty = threadIdx.y;
    const int t = ty * 16 + tx;
    const int lrow = t >> 2;
    const int lk4 = (t & 3) * 4;
    const int row0 = blockIdx.y * 64, col0 = blockIdx.x * 64;

    float acc[4][4] = {};

    for (int k0 = 0; k0 < D; k0 += 16) {
        const float4 xv = *(const float4*)&X[(row0 + lrow) * D + k0 + lk4];
        const float4 yv = *(const float4*)&Y[(col0 + lrow) * D + k0 + lk4];
        Xs[lk4 + 0][lrow] = xv.x; Xs[lk4 + 1][lrow] = xv.y;
        Xs[lk4 + 2][lrow] = xv.z; Xs[lk4 + 3][lrow] = xv.w;
        Ys[lk4 + 0][lrow] = yv.x; Ys[lk4 + 1][lrow] = yv.y;
        Ys[lk4 + 2][lrow] = yv.z; Ys[lk4 + 3][lrow] = yv.w;
        __syncthreads();
#pragma unroll
        for (int kk = 0; kk < 16; kk++) {
            const float4 a = *(const float4*)&Xs[kk][ty * 4];
            const float4 bb = *(const float4*)&Ys[kk][tx * 4];
            acc[0][0] += a.x * bb.x; acc[0][1] += a.x * bb.y; acc[0][2] += a.x * bb.z; acc[0][3] += a.x * bb.w;
            acc[1][0] += a.y * bb.x; acc[1][1] += a.y * bb.y; acc[1][2] += a.y * bb.z; acc[1][3] += a.y * bb.w;
            acc[2][0] += a.z * bb.x; acc[2][1] += a.z * bb.y; acc[2][2] += a.z * bb.z; acc[2][3] += a.z * bb.w;
            acc[3][0] += a.w * bb.x; acc[3][1] += a.w * bb.y; acc[3][2] += a.w * bb.z; acc[3][3] += a.w * bb.w;
        }
        __syncthreads();
    }

#pragma unroll
    for (int r = 0; r < 4; r++) {
        float4 o;
        float* op = &o.x;
#pragma unroll
        for (int c = 0; c < 4; c++) {
            const float x = acc[r][c];
            const float l = log1pf(expf(-fabsf(x)));
            op[c] = which ? (fminf(x, 0.0f) - l)     // log_sigmoid
                          : (fmaxf(x, 0.0f) + l);   // softplus
        }
        *(float4*)&C[(size_t)(row0 + ty * 4 + r) * M + col0 + tx * 4] = o;
    }
}

// ---------------------------------------------------------------------------
// Row-major theta,A -> compact-diag interleaved float2 {theta, A}, scaled by
// log2(e) so the DP kernel can use native exp2/log2 (p-ratios are invariant).
// ---------------------------------------------------------------------------
__global__ __launch_bounds__(256)
void reorder_in_kernel(const float* __restrict__ theta, const float* __restrict__ A,
                       float2* __restrict__ TAD)
{
    __shared__ float T[64][67];
    __shared__ float Ag[64][67];
    const int b = blockIdx.z;
    const float* ts = theta + (size_t)b * NM;
    const float* as = A + (size_t)b * NM;
    float2* dst = TAD + (size_t)b * NM;
    const int r0 = blockIdx.y * 64, c0 = blockIdx.x * 64;
    const int t = threadIdx.x, lane = t & 63, wv = t >> 6;

#pragma unroll
    for (int e = 0; e < 16; e++) {
        const int r = wv * 16 + e;
        T[r][lane]  = ts[(size_t)(r0 + r) * M + c0 + lane];
        Ag[r][lane] = as[(size_t)(r0 + r) * M + c0 + lane];
    }
    __syncthreads();
    for (int dd = wv; dd < 127; dd += 4) {
        const int kd = r0 + c0 + dd;
        const int rlo = max(0, dd - 63);
        const int L = min(63, dd) - rlo + 1;
        if (lane < L) {
            const int rloc = rlo + lane;
            const int gr = r0 + rloc;
            dst[diag_off(kd) + gr - max(0, kd - 511)] =
                make_float2(T[rloc][dd - rloc] * LOG2E, Ag[rloc][dd - rloc] * LOG2E);
        }
    }
}

// ---------------------------------------------------------------------------
// Compact-diag E -> row-major aln.
// ---------------------------------------------------------------------------
__global__ __launch_bounds__(256)
void reorder_out_kernel(const float* __restrict__ ED, float* __restrict__ aln)
{
    __shared__ float T[64][67];
    const int b = blockIdx.z;
    const float* src = ED + (size_t)b * NM;
    float* dst = aln + (size_t)b * NM;
    const int r0 = blockIdx.y * 64, c0 = blockIdx.x * 64;
    const int t = threadIdx.x, lane = t & 63, wv = t >> 6;

    for (int dd = wv; dd < 127; dd += 4) {
        const int kd = r0 + c0 + dd;
        const int rlo = max(0, dd - 63);
        const int L = min(63, dd) - rlo + 1;
        if (lane < L) {
            const int rloc = rlo + lane;
            const int gr = r0 + rloc;
            T[rloc][dd - rloc] = src[diag_off(kd) + gr - max(0, kd - 511)];
        }
    }
    __syncthreads();
#pragma unroll
    for (int e = 0; e < 16; e++) {
        const int r = wv * 16 + e;
        dst[(size_t)(r0 + r) * M + c0 + lane] = T[r][lane];
    }
}

// ---------------------------------------------------------------------------
// Chunk barrier: LDS-only drain + raw s_barrier. Global loads/stores stay in
// flight across the barrier (compiler inserts counted vmcnt at the use sites).
// sched_barrier(0) pins LDS ops / ring reads on the right side (rule #18).
// ---------------------------------------------------------------------------
#define CHUNK_BARRIER                          \
    __builtin_amdgcn_sched_barrier(0);         \
    asm volatile("s_waitcnt lgkmcnt(0)");      \
    __builtin_amdgcn_s_barrier();              \
    __builtin_amdgcn_sched_barrier(0);

#define DECL8(P) float2 P##0, P##1, P##2, P##3, P##4, P##5, P##6, P##7;

// ---------------------------------------------------------------------------
// Forward soft-NW. skew=8 wave pipeline; depth-2 (triple-buffer) register
// prefetch in NAMED scalars (no scratch demotion); base-2 math; interior
// chunks drop all per-lane guards.
// ---------------------------------------------------------------------------
#define F_PREF(P, c1) {                                        \
    const int kb1 = 8 * (c1) - w8;                             \
    P##0 = tab[diag_flat_clamped(kb1 + 0, tid)];               \
    P##1 = tab[diag_flat_clamped(kb1 + 1, tid)];               \
    P##2 = tab[diag_flat_clamped(kb1 + 2, tid)];               \
    P##3 = tab[diag_flat_clamped(kb1 + 3, tid)];               \
    P##4 = tab[diag_flat_clamped(kb1 + 4, tid)];               \
    P##5 = tab[diag_flat_clamped(kb1 + 5, tid)];               \
    P##6 = tab[diag_flat_clamped(kb1 + 6, tid)];               \
    P##7 = tab[diag_flat_clamped(kb1 + 7, tid)];               \
}

#define F_CORE(kd_, TA, sh1v, dgv) {                           \
    const float th = TA.x, a = TA.y;                           \
    const float x0 = a + sh1v;                                 \
    const float x2 = a + vprev;                                \
    const float mx = fmaxf(fmaxf(x0, dgv), x2);                \
    const float e0 = EXP2F(x0 - mx);                           \
    const float e1 = EXP2F(dgv - mx);                          \
    const float e2 = EXP2F(x2 - mx);                           \
    const float sum = e0 + e1 + e2;                            \
    const float inv = __builtin_amdgcn_rcpf(sum);              \
    const int fi = diag_off(kd_) + tid - max(0, (kd_) - 511);  \
    pb[fi] = make_float2(e0 * inv, e2 * inv);                  \
    vprev = th + mx + LOG2F(sum);                              \
    if (lane == 63) ring[w][(kd_) & 63] = vprev;               \
}

// interior: every lane valid, jj>=1 guaranteed -> no selects, no exec juggling
#define F_STEP_I(s, TA, RG) {                                  \
    const int kd = kb + (s);                                   \
    float sh1 = dpp_shr1(vprev);                               \
    if (lane == 0) sh1 = RG;                                   \
    const float dgv = sh1_d;                                   \
    sh1_d = sh1;                                               \
    F_CORE(kd, TA, sh1, dgv)                                   \
}

#define F_STEP_G(s, TA, RG) {                                  \
    const int kd = kb + (s);                                   \
    const int jj = kd - tid;                                   \
    float sh1 = dpp_shr1(vprev);                               \
    if (lane == 0) sh1 = RG;                                   \
    const float dgv = (jj == 0) ? ((tid == 0) ? 0.0f : NEG) : sh1_d; \
    sh1_d = sh1;                                               \
    if (jj >= 0 && jj < M) { F_CORE(kd, TA, sh1, dgv) }        \
}

#define F_CHUNK(c_, CUR, NXT) {                                \
    const int c = (c_);                                        \
    if (c + 2 >= ca && c + 2 <= cb) { F_PREF(NXT, c + 2) }     \
    if (c >= ca && c <= cb) {                                  \
        const int kb = 8 * c - w8;                             \
        float r0 = NEG, r1 = NEG, r2 = NEG, r3 = NEG,          \
              r4 = NEG, r5 = NEG, r6 = NEG, r7 = NEG;          \
        if (w > 0) {                                           \
            r0 = ring[w - 1][(kb - 1) & 63];                   \
            r1 = ring[w - 1][(kb + 0) & 63];                   \
            r2 = ring[w - 1][(kb + 1) & 63];                   \
            r3 = ring[w - 1][(kb + 2) & 63];                   \
            r4 = ring[w - 1][(kb + 3) & 63];                   \
            r5 = ring[w - 1][(kb + 4) & 63];                   \
            r6 = ring[w - 1][(kb + 5) & 63];                   \
            r7 = ring[w - 1][(kb + 6) & 63];                   \
        }                                                      \
        const int kr = kb - 64 * w;                            \
        if (kr >= 64 && kr <= 504) {                           \
            F_STEP_I(0, CUR##0, r0) F_STEP_I(1, CUR##1, r1)    \
            F_STEP_I(2, CUR##2, r2) F_STEP_I(3, CUR##3, r3)    \
            F_STEP_I(4, CUR##4, r4) F_STEP_I(5, CUR##5, r5)    \
            F_STEP_I(6, CUR##6, r6) F_STEP_I(7, CUR##7, r7)    \
        } else {                                               \
            F_STEP_G(0, CUR##0, r0) F_STEP_G(1, CUR##1, r1)    \
            F_STEP_G(2, CUR##2, r2) F_STEP_G(3, CUR##3, r3)    \
            F_STEP_G(4, CUR##4, r4) F_STEP_G(5, CUR##5, r5)    \
            F_STEP_G(6, CUR##6, r6) F_STEP_G(7, CUR##7, r7)    \
        }                                                      \
    }                                                          \
    CHUNK_BARRIER                                              \
}

__global__ __launch_bounds__(512)
void nw_forward_kernel(const float2* __restrict__ TAD, float2* __restrict__ pD)
{
    __shared__ float ring[8][64];
    const int b = blockIdx.x;
    const int tid = threadIdx.x;
    const int w = __builtin_amdgcn_readfirstlane(tid >> 6);
    const int lane = tid & 63;
    const int w8 = 8 * w;
    const float2* tab = TAD + (size_t)b * NM;
    float2* pb = pD + (size_t)b * NM;

    for (int x = tid; x < 8 * 64; x += 512) ((float*)ring)[x] = NEG;
    __syncthreads();

    const int ca = 9 * w, cb = 9 * w + 71;

    DECL8(fa) DECL8(fb) DECL8(fc)
    F_PREF(fa, 0)
    F_PREF(fb, 1)

    float vprev = NEG, sh1_d = NEG;

    for (int c2 = 0; c2 < NCHUNK; c2 += 3) {
        F_CHUNK(c2 + 0, fa, fc)
        F_CHUNK(c2 + 1, fb, fa)
        F_CHUNK(c2 + 2, fc, fb)
    }
}

// ---------------------------------------------------------------------------
// Backward adjoint, q-product form, mirrored skew (wave 7 leads), K0 = 1078.
// Same triple-buffer + raw-barrier + interior-specialization structure.
// ---------------------------------------------------------------------------
#define B_PREF(P, c1) {                                        \
    const int kb1 = 1078 - 8 * (c1) - w8;                      \
    P##0 = pb[diag_flat_clamped(kb1 - 0, tid)];                \
    P##1 = pb[diag_flat_clamped(kb1 - 1, tid)];                \
    P##2 = pb[diag_flat_clamped(kb1 - 2, tid)];                \
    P##3 = pb[diag_flat_clamped(kb1 - 3, tid)];                \
    P##4 = pb[diag_flat_clamped(kb1 - 4, tid)];                \
    P##5 = pb[diag_flat_clamped(kb1 - 5, tid)];                \
    P##6 = pb[diag_flat_clamped(kb1 - 6, tid)];                \
    P##7 = pb[diag_flat_clamped(kb1 - 7, tid)];                \
}

#define B_CORE(kd_, PP, suv, sdv, TERMFIX) {                   \
    float e = suv + sdv + ql1;                                 \
    TERMFIX                                                    \
    const float pu = PP.x, pl = PP.y;                          \
    const float pd = 1.0f - pu - pl;                           \
    const float qu = pu * e, qd = pd * e, ql = pl * e;         \
    const int fi = diag_off(kd_) + tid - max(0, (kd_) - 511);  \
    eb[fi] = e;                                                \
    qd2 = qd1; qd1 = qd; qu1 = qu; ql1 = ql;                   \
    if (lane == 0) {                                           \
        ring_u[w][(kd_) & 63] = qu;                            \
        ring_d[w][(kd_) & 63] = qd;                            \
    }                                                          \
}

#define B_STEP_I(s, PP, RU, RD) {                              \
    const int kd = kb - (s);                                   \
    float su = dpp_shl1(qu1);                                  \
    float sd = dpp_shl1(qd2);                                  \
    if (lane == 63) { su = RU; sd = RD; }                      \
    B_CORE(kd, PP, su, sd, )                                   \
}

#define B_STEP_G(s, PP, RU, RD) {                              \
    const int kd = kb - (s);                                   \
    const int jj = kd - tid;                                   \
    float su = dpp_shl1(qu1);                                  \
    float sd = dpp_shl1(qd2);                                  \
    if (lane == 63) { su = RU; sd = RD; }                      \
    if (jj >= 0 && jj < M) {                                   \
        B_CORE(kd, PP, su, sd,                                 \
               if (tid == N - 1 && jj == M - 1) e = 1.0f;)     \
    }                                                          \
}

#define B_CHUNK(c_, CUR, NXT) {                                \
    const int c = (c_);                                        \
    if (c + 2 >= ca && c + 2 <= cb) { B_PREF(NXT, c + 2) }     \
    if (c >= ca && c <= cb) {                                  \
        const int kb = 1078 - 8 * c - w8;                      \
        float ru0 = 0.f, ru1 = 0.f, ru2 = 0.f, ru3 = 0.f,      \
              ru4 = 0.f, ru5 = 0.f, ru6 = 0.f, ru7 = 0.f;      \
        float rd0 = 0.f, rd1 = 0.f, rd2 = 0.f, rd3 = 0.f,      \
              rd4 = 0.f, rd5 = 0.f, rd6 = 0.f, rd7 = 0.f;      \
        if (w < 7) {                                           \
            ru0 = ring_u[w + 1][(kb + 1) & 63]; rd0 = ring_d[w + 1][(kb + 2) & 63]; \
            ru1 = ring_u[w + 1][(kb + 0) & 63]; rd1 = ring_d[w + 1][(kb + 1) & 63]; \
            ru2 = ring_u[w + 1][(kb - 1) & 63]; rd2 = ring_d[w + 1][(kb + 0) & 63]; \
            ru3 = ring_u[w + 1][(kb - 2) & 63]; rd3 = ring_d[w + 1][(kb - 1) & 63]; \
            ru4 = ring_u[w + 1][(kb - 3) & 63]; rd4 = ring_d[w + 1][(kb - 2) & 63]; \
            ru5 = ring_u[w + 1][(kb - 4) & 63]; rd5 = ring_d[w + 1][(kb - 3) & 63]; \
            ru6 = ring_u[w + 1][(kb - 5) & 63]; rd6 = ring_d[w + 1][(kb - 4) & 63]; \
            ru7 = ring_u[w + 1][(kb - 6) & 63]; rd7 = ring_d[w + 1][(kb - 5) & 63]; \
        }                                                      \
        const int krb = kb - 64 * w;                           \
        if (krb >= 70 && krb <= 511) {                         \
            B_STEP_I(0, CUR##0, ru0, rd0) B_STEP_I(1, CUR##1, ru1, rd1) \
            B_STEP_I(2, CUR##2, ru2, rd2) B_STEP_I(3, CUR##3, ru3, rd3) \
            B_STEP_I(4, CUR##4, ru4, rd4) B_STEP_I(5, CUR##5, ru5, rd5) \
            B_STEP_I(6, CUR##6, ru6, rd6) B_STEP_I(7, CUR##7, ru7, rd7) \
        } else {                                               \
            B_STEP_G(0, CUR##0, ru0, rd0) B_STEP_G(1, CUR##1, ru1, rd1) \
            B_STEP_G(2, CUR##2, ru2, rd2) B_STEP_G(3, CUR##3, ru3, rd3) \
            B_STEP_G(4, CUR##4, ru4, rd4) B_STEP_G(5, CUR##5, ru5, rd5) \
            B_STEP_G(6, CUR##6, ru6, rd6) B_STEP_G(7, CUR##7, ru7, rd7) \
        }                                                      \
    }                                                          \
    CHUNK_BARRIER                                              \
}

__global__ __launch_bounds__(512)
void nw_backward_kernel(const float2* __restrict__ pD, float* __restrict__ ED)
{
    __shared__ float ring_u[8][64];
    __shared__ float ring_d[8][64];
    const int b = blockIdx.x;
    const int tid = threadIdx.x;
    const int w = __builtin_amdgcn_readfirstlane(tid >> 6);
    const int lane = tid & 63;
    const int w8 = 8 * w;
    const float2* pb = pD + (size_t)b * NM;
    float* eb = ED + (size_t)b * NM;

    for (int x = tid; x < 8 * 64; x += 512) {
        ((float*)ring_u)[x] = 0.0f;
        ((float*)ring_d)[x] = 0.0f;
    }
    __syncthreads();

    const int ca = 63 - 9 * w, cb = 134 - 9 * w;

    DECL8(ba) DECL8(bb) DECL8(bc)
    B_PREF(ba, 0)
    B_PREF(bb, 1)

    float qu1 = 0.0f, qd1 = 0.0f, qd2 = 0.0f, ql1 = 0.0f;

    for (int c2 = 0; c2 < NCHUNK; c2 += 3) {
        B_CHUNK(c2 + 0, ba, bc)
        B_CHUNK(c2 + 1, bb, ba)
        B_CHUNK(c2 + 2, bc, bb)
    }
}

// ---------------------------------------------------------------------------
extern "C" void kernel_launch(void* const* d_in, const int* in_sizes, int n_in,
                              void* d_out, int out_size, void* d_ws, size_t ws_size,
                              hipStream_t stream) {
    const float* zx = (const float*)d_in[0];
    const float* zy = (const float*)d_in[1];
    const float* gx = (const float*)d_in[2];
    const float* gy = (const float*)d_in[3];

    float* aln   = (float*)d_out;               // output 0: [B,N,M]
    float* theta = aln + B * NM;                // output 1
    float* Amat  = theta + B * NM;              // output 2

    float2* TAD = (float2*)d_ws;                // {theta,A}*log2e diag-interleaved
    float2* pD  = TAD + B * NM;                 // {p_up,p_lf} diag-interleaved
    float*  ED  = (float*)d_ws;                 // overlays TAD (dead after forward)

    gemm_act_kernel<<<dim3(8, 8, B * 2), dim3(16, 16), 0, stream>>>(zx, zy, gx, gy, theta, Amat);
    reorder_in_kernel<<<dim3(8, 8, B), 256, 0, stream>>>(theta, Amat, TAD);
    nw_forward_kernel<<<B, 512, 0, stream>>>(TAD, pD);
    nw_backward_kernel<<<B, 512, 0, stream>>>(pD, ED);
    reorder_out_kernel<<<dim3(8, 8, B), 256, 0, stream>>>(ED, aln);
}